// Round 1
// 551.284 us; speedup vs baseline: 1.0818x; 1.0818x over previous
//
#include <hip/hip_runtime.h>
#include <hip/hip_bf16.h>

// SimpleBNN: out = sign(sign(sign(x)@sign(w1)T + b1) @ sign(w2)T + b2) @ w3T + b3
// Layers 1-2: exact ternary GEMM via MX-fp4 MFMA (K=128/inst, scale=1.0):
//   fp4 e2m1 represents {-1,0,+1} exactly; products +-1, |sums|<=4096 << 2^24
//   with fp32 accumulation -> bit-exact vs the numpy reference.
// Layer 3 (this round): a2 is ternary -> store as i8 (exact) and run an
//   i8xi8 GEMM (v_mfma_i32_16x16x64_i8) against w3 quantized to i8 with a
//   PER-ROW scale (s_n = rowmax/127). Per-element quant error <= s/2 ~ 6e-5;
//   over K=4096 random-sign sums expected absmax ~0.013-0.02, same order as
//   the previous bf16-w3 absmax (0.0156), well under the 6.5e-2 threshold.
//   vs the old bf16 gemm_bt: MFMA inst count and staging bytes per block
//   halve (K=64/inst vs 32), A operand halves (32 MB i8 vs 64 MB bf16).
//
// LDS tiles use the XOR-swizzled layout (16B granules):
//   slot s in [0,512) <-> (row = s>>2, chunk c = (s&3) ^ ((row>>1)&3))
// staging stays coalesced (16 x 64B lines/wave) and fragment ds_read_b128s are
// conflict-free (2-way aliasing = free, m136). Byte addressing is IDENTICAL
// across the i8 and fp4 kernels; only the element interpretation changes.
// Any consistent within-row k-permutation applied to both A and B cancels in
// A@B^T, so pack-order conventions are risk-free.

typedef __attribute__((ext_vector_type(4))) float f32x4;
typedef __attribute__((ext_vector_type(4))) int   i32x4;
typedef __attribute__((ext_vector_type(8))) int   i32x8;

#define BM 128
#define BN 128

__device__ __forceinline__ void async_copy16(const void* g, void* l) {
  __builtin_amdgcn_global_load_lds(
      (const __attribute__((address_space(1))) void*)g,
      (__attribute__((address_space(3))) void*)l,
      16, 0, 0);
}

__device__ __forceinline__ char sign8(float v) {
  return (v > 0.f) ? (char)1 : ((v < 0.f) ? (char)-1 : (char)0);
}
// fp4 e2m1 nibble for sign: +1 -> 0x2, -1 -> 0xA, 0 -> 0x0
__device__ __forceinline__ unsigned nib4(float v) {
  return (v > 0.f) ? 0x2u : ((v < 0.f) ? 0xAu : 0x0u);
}

// fp32 -> packed fp4 sign, 8 elems/thread (4B coalesced stores)
__global__ void sign_pack_fp4(const float* __restrict__ in, unsigned* __restrict__ out, int n8) {
  int i = blockIdx.x * blockDim.x + threadIdx.x;
  if (i >= n8) return;
  const float4* p = (const float4*)in + (size_t)i * 2;
  float4 v0 = p[0], v1 = p[1];
  unsigned b0 = nib4(v0.x) | (nib4(v0.y) << 4);
  unsigned b1 = nib4(v0.z) | (nib4(v0.w) << 4);
  unsigned b2 = nib4(v1.x) | (nib4(v1.y) << 4);
  unsigned b3 = nib4(v1.z) | (nib4(v1.w) << 4);
  out[i] = b0 | (b1 << 8) | (b2 << 16) | (b3 << 24);
}

// i8 {-1,0,1} -> packed fp4, 8 elems/thread
__global__ void repack_i8_fp4(const char* __restrict__ in, unsigned* __restrict__ out, int n8) {
  int i = blockIdx.x * blockDim.x + threadIdx.x;
  if (i >= n8) return;
  int2 w = ((const int2*)in)[i];
  union { int2 d; char c[8]; } u; u.d = w;
  unsigned r = 0;
#pragma unroll
  for (int j = 0; j < 8; ++j) {
    char v = u.c[j];
    unsigned nb = (v == 1) ? 0x2u : ((v == (char)-1) ? 0xAu : 0x0u);
    r |= nb << (4 * j);
  }
  out[i] = r;
}

// w3 [1000,4096] fp32 -> i8 [1024,4096] with per-row scale s[row]=rowmax/127;
// rows >= rows_valid zero-filled with scale 0. One 256-thread block per row.
__global__ __launch_bounds__(256)
void w3_quant(const float* __restrict__ in, char* __restrict__ out,
              float* __restrict__ scale, int rows_valid) {
  const int row = blockIdx.x;
  const int tid = threadIdx.x;
  int* orow = (int*)(out + (size_t)row * 4096);
  if (row >= rows_valid) {
#pragma unroll
    for (int j = 0; j < 4; ++j) orow[j * 256 + tid] = 0;
    if (tid == 0) scale[row] = 0.f;
    return;
  }
  const float4* p = (const float4*)(in + (size_t)row * 4096);
  float4 v[4];
  float amax = 0.f;
#pragma unroll
  for (int j = 0; j < 4; ++j) {
    v[j] = p[j * 256 + tid];
    amax = fmaxf(amax, fmaxf(fmaxf(fabsf(v[j].x), fabsf(v[j].y)),
                             fmaxf(fabsf(v[j].z), fabsf(v[j].w))));
  }
#pragma unroll
  for (int m = 32; m >= 1; m >>= 1)
    amax = fmaxf(amax, __shfl_xor(amax, m, 64));
  __shared__ float wmax[4];
  if ((tid & 63) == 0) wmax[tid >> 6] = amax;
  __syncthreads();
  const float rowmax = fmaxf(fmaxf(wmax[0], wmax[1]), fmaxf(wmax[2], wmax[3]));
  const float inv = (rowmax > 0.f) ? 127.f / rowmax : 0.f;
#pragma unroll
  for (int j = 0; j < 4; ++j) {
    int q0 = (int)rintf(v[j].x * inv);
    int q1 = (int)rintf(v[j].y * inv);
    int q2 = (int)rintf(v[j].z * inv);
    int q3 = (int)rintf(v[j].w * inv);
    unsigned r = ((unsigned)(unsigned char)(char)q0)
               | ((unsigned)(unsigned char)(char)q1 << 8)
               | ((unsigned)(unsigned char)(char)q2 << 16)
               | ((unsigned)(unsigned char)(char)q3 << 24);
    orow[j * 256 + tid] = (int)r;
  }
  if (tid == 0) scale[row] = rowmax * (1.f / 127.f);
}

// ---------------------------------------------------------------------------
// Ternary MX-fp4 GEMM: Ci8 = sign(A @ B^T + bias). A [M,Kb] / B [N,Kb] packed
// fp4 (Kb = K/2 bytes). 128x128 tile, one barrier-pair covers K=128 (64B/row),
// mfma_scale_f32_16x16x128_f8f6f4 (cbsz=blgp=4 -> fp4, scales 0x7F = 2^0).
// 4 waves x 4x4 16x16 tiles. Fragment: lane holds 16B = 32 fp4 of k-quadrant
// (lane>>4)*32, rows fr=lane&15.
// ---------------------------------------------------------------------------
__global__ __launch_bounds__(256)
void gemm_fp4(const unsigned char* __restrict__ A,
              const unsigned char* __restrict__ B,
              const float* __restrict__ bias,
              char* __restrict__ Ci8,
              int Kb, int ldc)
{
  __shared__ unsigned char As[128 * 64];   // 8 KB, swizzled 16B granules
  __shared__ unsigned char Bs[128 * 64];   // 8 KB

  const int tid  = threadIdx.x;
  const int lane = tid & 63;
  const int wid  = tid >> 6;
  const int wy   = wid >> 1;
  const int wx   = wid & 1;

  const int m0 = blockIdx.y * BM;
  const int n0 = blockIdx.x * BN;

  // staging: thread t fills slots t (rows 0..63) and t+256 (rows 64..127)
  const int r1 = tid >> 2;
  const int r2 = r1 + 64;
  const int c1 = (tid & 3) ^ ((r1 >> 1) & 3);
  const int c2 = (tid & 3) ^ ((r2 >> 1) & 3);
  const unsigned char* Ag1 = A + (size_t)(m0 + r1) * Kb + c1 * 16;
  const unsigned char* Ag2 = A + (size_t)(m0 + r2) * Kb + c2 * 16;
  const unsigned char* Bg1 = B + (size_t)(n0 + r1) * Kb + c1 * 16;
  const unsigned char* Bg2 = B + (size_t)(n0 + r2) * Kb + c2 * 16;
  unsigned char* Asl1 = As + tid * 16;
  unsigned char* Asl2 = As + (tid + 256) * 16;
  unsigned char* Bsl1 = Bs + tid * 16;
  unsigned char* Bsl2 = Bs + (tid + 256) * 16;

  f32x4 acc[4][4];
#pragma unroll
  for (int i = 0; i < 4; ++i)
#pragma unroll
    for (int j = 0; j < 4; ++j)
      acc[i][j] = (f32x4){0.f, 0.f, 0.f, 0.f};

  const int fr  = lane & 15;                      // row within 16-tile
  const int kc  = lane >> 4;                      // k-quadrant 0..3
  const int swz = (kc ^ ((fr >> 1) & 3)) * 16;    // swizzled granule byte offset

  for (int k0 = 0; k0 < Kb; k0 += 64) {           // 64 bytes = 128 fp4 per iter
    async_copy16(Ag1 + k0, Asl1);
    async_copy16(Ag2 + k0, Asl2);
    async_copy16(Bg1 + k0, Bsl1);
    async_copy16(Bg2 + k0, Bsl2);
    __syncthreads();   // drains vmcnt -> staged data visible

    i32x8 a[4], b[4];
#pragma unroll
    for (int i = 0; i < 4; ++i) {
      i32x4 t = *(const i32x4*)(As + (wy * 64 + i * 16 + fr) * 64 + swz);
      a[i] = (i32x8){t[0], t[1], t[2], t[3], 0, 0, 0, 0};   // fp4 reads regs 0..3 only
    }
#pragma unroll
    for (int j = 0; j < 4; ++j) {
      i32x4 t = *(const i32x4*)(Bs + (wx * 64 + j * 16 + fr) * 64 + swz);
      b[j] = (i32x8){t[0], t[1], t[2], t[3], 0, 0, 0, 0};
    }

#pragma unroll
    for (int i = 0; i < 4; ++i)
#pragma unroll
      for (int j = 0; j < 4; ++j)
        acc[i][j] = __builtin_amdgcn_mfma_scale_f32_16x16x128_f8f6f4(
            a[i], b[j], acc[i][j],
            4, 4,                 // cbsz=fp4(e2m1), blgp=fp4(e2m1)
            0, 0x7f7f7f7f,        // scale_a opsel, scale_a bytes = 127 -> 2^0
            0, 0x7f7f7f7f);       // scale_b
    __syncthreads();
  }

  // C/D layout (shape-determined, m121-m128): col=lane&15, row=(lane>>4)*4+reg
  const int ccol = lane & 15;
  const int crow = (lane >> 4) * 4;
#pragma unroll
  for (int i = 0; i < 4; ++i) {
    const int m = m0 + wy * 64 + i * 16 + crow;
#pragma unroll
    for (int j = 0; j < 4; ++j) {
      const int n = n0 + wx * 64 + j * 16 + ccol;
      const float bv = bias[n];
#pragma unroll
      for (int r = 0; r < 4; ++r) {
        float v = acc[i][j][r] + bv;
        Ci8[(size_t)(m + r) * ldc + n] = sign8(v);
      }
    }
  }
}

// ---------------------------------------------------------------------------
// i8 GEMM for layer 3: Cf = (A_i8 @ B_i8^T) * scale[n] + bias[n], guarded
// n < nvalid. A [M,K] i8 (ternary, exact), B [N,K] i8 (quantized w3).
// Same 128x128 swizzled-LDS structure; K=64 i8 per stage = 64B/row,
// v_mfma_i32_16x16x64_i8 (byte-layout identical to the fp4/bf16 kernels).
// |acc| <= 4096*127 << 2^31 -> exact integer accumulation.
// ---------------------------------------------------------------------------
__global__ __launch_bounds__(256)
void gemm_i8(const char* __restrict__ A,
             const char* __restrict__ B,
             const float* __restrict__ scale,
             const float* __restrict__ bias,
             float* __restrict__ Cf,
             int Kb, int ldc, int nvalid)
{
  __shared__ char As[128 * 64];
  __shared__ char Bs[128 * 64];

  const int tid  = threadIdx.x;
  const int lane = tid & 63;
  const int wid  = tid >> 6;
  const int wy   = wid >> 1;
  const int wx   = wid & 1;

  const int m0 = blockIdx.y * BM;
  const int n0 = blockIdx.x * BN;

  const int r1 = tid >> 2;
  const int r2 = r1 + 64;
  const int c1 = (tid & 3) ^ ((r1 >> 1) & 3);
  const int c2 = (tid & 3) ^ ((r2 >> 1) & 3);
  const char* Ag1 = A + (size_t)(m0 + r1) * Kb + c1 * 16;
  const char* Ag2 = A + (size_t)(m0 + r2) * Kb + c2 * 16;
  const char* Bg1 = B + (size_t)(n0 + r1) * Kb + c1 * 16;
  const char* Bg2 = B + (size_t)(n0 + r2) * Kb + c2 * 16;
  char* Asl1 = As + tid * 16;
  char* Asl2 = As + (tid + 256) * 16;
  char* Bsl1 = Bs + tid * 16;
  char* Bsl2 = Bs + (tid + 256) * 16;

  i32x4 acc[4][4];
#pragma unroll
  for (int i = 0; i < 4; ++i)
#pragma unroll
    for (int j = 0; j < 4; ++j)
      acc[i][j] = (i32x4){0, 0, 0, 0};

  const int fr  = lane & 15;
  const int kc  = lane >> 4;
  const int swz = (kc ^ ((fr >> 1) & 3)) * 16;

  for (int k0 = 0; k0 < Kb; k0 += 64) {           // 64 i8 = K-step 64
    async_copy16(Ag1 + k0, Asl1);
    async_copy16(Ag2 + k0, Asl2);
    async_copy16(Bg1 + k0, Bsl1);
    async_copy16(Bg2 + k0, Bsl2);
    __syncthreads();

    i32x4 a[4], b[4];
#pragma unroll
    for (int i = 0; i < 4; ++i)
      a[i] = *(const i32x4*)(As + (wy * 64 + i * 16 + fr) * 64 + swz);
#pragma unroll
    for (int j = 0; j < 4; ++j)
      b[j] = *(const i32x4*)(Bs + (wx * 64 + j * 16 + fr) * 64 + swz);

#pragma unroll
    for (int i = 0; i < 4; ++i)
#pragma unroll
      for (int j = 0; j < 4; ++j)
        acc[i][j] = __builtin_amdgcn_mfma_i32_16x16x64_i8(a[i], b[j], acc[i][j], 0, 0, 0);
    __syncthreads();
  }

  const int ccol = lane & 15;
  const int crow = (lane >> 4) * 4;
#pragma unroll
  for (int i = 0; i < 4; ++i) {
    const int m = m0 + wy * 64 + i * 16 + crow;
#pragma unroll
    for (int j = 0; j < 4; ++j) {
      const int n = n0 + wx * 64 + j * 16 + ccol;
      if (n >= nvalid) continue;
      const float sv = scale[n];
      const float bv = bias[n];
#pragma unroll
      for (int r = 0; r < 4; ++r) {
        Cf[(size_t)(m + r) * ldc + n] = (float)acc[i][j][r] * sv + bv;
      }
    }
  }
}

extern "C" void kernel_launch(void* const* d_in, const int* in_sizes, int n_in,
                              void* d_out, int out_size, void* d_ws, size_t ws_size,
                              hipStream_t stream) {
  const float* x  = (const float*)d_in[0];   // [8192,4096]
  const float* w1 = (const float*)d_in[1];   // [4096,4096]
  const float* b1 = (const float*)d_in[2];   // [4096]
  const float* w2 = (const float*)d_in[3];   // [4096,4096]
  const float* b2 = (const float*)d_in[4];   // [4096]
  const float* w3 = (const float*)d_in[5];   // [1000,4096]
  const float* b3 = (const float*)d_in[6];   // [1000]

  const int Mb = 8192, H = 4096, C = 1000, Cpad = 1024;
  const int Kb = H / 2;                      // packed fp4 bytes per row

  // workspace layout (120 MB used):
  //   [0,16M)    xp   fp4-packed sign(x)       [8192,2048B]
  //   [16,24M)   w1p  fp4-packed sign(w1)      [4096,2048B]
  //   [24,32M)   w2p  fp4-packed sign(w2)      [4096,2048B]
  //   [32,36M)   w3q  i8 [1024,4096] padded
  //   [36,36M+4K) s3  fp32 per-row scales [1024]
  //   [40,72M)   a1   i8   [8192,4096]
  //   [72,88M)   a1p  fp4-packed a1            [8192,2048B]
  //   [88,120M)  a2   i8   [8192,4096]
  char* ws = (char*)d_ws;
  unsigned*       xp  = (unsigned*)(ws);
  unsigned*       w1p = (unsigned*)(ws + (size_t)16777216);
  unsigned*       w2p = (unsigned*)(ws + (size_t)25165824);
  char*           w3q = ws + (size_t)33554432;
  float*          s3  = (float*)(ws + (size_t)37748736);
  char*           a1  = ws + (size_t)41943040;
  unsigned*       a1p = (unsigned*)(ws + (size_t)75497472);
  char*           a2  = ws + (size_t)92274688;

  sign_pack_fp4<<<(Mb * H / 8 + 255) / 256, 256, 0, stream>>>(x,  xp,  Mb * H / 8);
  sign_pack_fp4<<<(H * H / 8 + 255) / 256, 256, 0, stream>>>(w1, w1p, H * H / 8);
  sign_pack_fp4<<<(H * H / 8 + 255) / 256, 256, 0, stream>>>(w2, w2p, H * H / 8);
  w3_quant<<<Cpad, 256, 0, stream>>>(w3, w3q, s3, C);

  dim3 blk(256);
  // layer 1: a1 = sign(sign(x) @ sign(w1)^T + b1)   [exact, MX-fp4]
  gemm_fp4<<<dim3(H / BN, Mb / BM), blk, 0, stream>>>(
      (const unsigned char*)xp, (const unsigned char*)w1p, b1, a1, Kb, H);
  // repack ternary a1 (i8) -> fp4 for layer 2
  repack_i8_fp4<<<(Mb * H / 8 + 255) / 256, 256, 0, stream>>>(a1, a1p, Mb * H / 8);
  // layer 2: a2 = sign(a1 @ sign(w2)^T + b2)        [exact, MX-fp4, i8 out]
  gemm_fp4<<<dim3(H / BN, Mb / BM), blk, 0, stream>>>(
      (const unsigned char*)a1p, (const unsigned char*)w2p, b2, a2, Kb, H);
  // layer 3: out = a2 @ w3q^T * s3 + b3             [exact-ternary x i8 GEMM]
  gemm_i8<<<dim3(Cpad / BN, Mb / BM), blk, 0, stream>>>(
      a2, w3q, s3, b3, (float*)d_out, H, C, C);
}